// Round 1
// baseline (266.347 us; speedup 1.0000x reference)
//
#include <hip/hip_runtime.h>

// Problem constants (from reference)
#define BATCH 16384
#define NF    512
#define DEG   8
#define NC    10
#define KB    8

// Tiling
#define RB       64    // rows per block
#define FC       128   // feature chunk
#define PITCH    129   // FC + 1 (phase-2 reads conflict-free: 129 % 32 == 1)
#define NTHREADS 512   // 8 waves
#define NWAVES   8
#define FPW      (FC / NWAVES)   // 16 features per wave per chunk

__device__ __forceinline__ float fast_tanh(float x) {
    // tanh(x) = 1 - 2/(exp(2x)+1); __expf -> v_exp_f32 path
    float e = __expf(2.0f * x);
    return 1.0f - 2.0f * __builtin_amdgcn_rcpf(e + 1.0f);
}

__device__ __forceinline__ float fast_sigmoid(float x) {
    return __builtin_amdgcn_rcpf(1.0f + __expf(-x));
}

__global__ __launch_bounds__(NTHREADS) void qkan_kernel(
    const float* __restrict__ X,        // (B, F)
    const float* __restrict__ lcu_w,    // (F, DEG)
    const float* __restrict__ alpha,    // (F, DEG)
    const float* __restrict__ coeff,    // (C, F, KB)
    const float* __restrict__ base,     // (C, F)
    const float* __restrict__ bias,     // (C)
    float* __restrict__ out)            // (B, C)
{
    __shared__ float s_sum[RB * PITCH];              // 33 KB: summed tile
    __shared__ float s_red[NWAVES * RB * NC];        // 20 KB: cross-wave reduce

    const int t    = threadIdx.x;
    const int row0 = blockIdx.x * RB;
    const int wave = __builtin_amdgcn_readfirstlane(t >> 6);
    const int lane = t & 63;

    float acc[NC];
#pragma unroll
    for (int c = 0; c < NC; ++c) acc[c] = 0.0f;

    for (int chunk = 0; chunk < NF / FC; ++chunk) {
        const int fbase = chunk * FC;

        // ---------- phase 1: elementwise -> summed(b,f) into LDS ----------
        {
            const int f4   = t & 31;    // float4 column within chunk
            const int rsub = t >> 5;    // 0..15
#pragma unroll
            for (int it = 0; it < RB / 16; ++it) {
                const int r = rsub + it * 16;
                const float4 xv = *(const float4*)(X + (row0 + r) * NF + fbase + f4 * 4);
                float xs[4] = {xv.x, xv.y, xv.z, xv.w};
                float sums[4];
#pragma unroll
                for (int i = 0; i < 4; ++i) {
                    const int f = fbase + f4 * 4 + i;
                    float x = 0.99f * fast_tanh(xs[i]);

                    const float4 w0 = *(const float4*)(lcu_w + f * DEG);
                    const float4 w1 = *(const float4*)(lcu_w + f * DEG + 4);
                    const float4 a0 = *(const float4*)(alpha + f * DEG);
                    const float4 a1 = *(const float4*)(alpha + f * DEG + 4);
                    float wv[8] = {w0.x, w0.y, w0.z, w0.w, w1.x, w1.y, w1.z, w1.w};
                    float av[8] = {a0.x, a0.y, a0.z, a0.w, a1.x, a1.y, a1.z, a1.w};

                    // Chebyshev recurrence T_1..T_8, dot with w, l1 norm
                    float tkm1 = 1.0f, tk = x;
                    const float x2 = 2.0f * x;
                    float num = 0.0f, den = 1e-8f;
#pragma unroll
                    for (int d = 0; d < DEG; ++d) {
                        num = fmaf(wv[d], tk, num);
                        den += fabsf(wv[d]);
                        float tn = fmaf(x2, tk, -tkm1);
                        tkm1 = tk; tk = tn;
                    }
                    const float lcu = num * __builtin_amdgcn_rcpf(den);

                    float ss = 0.0f;
#pragma unroll
                    for (int d = 0; d < DEG; ++d)
                        ss += __sinf(lcu * av[d]);
                    sums[i] = 0.125f * ss;
                }
                // scalar LDS writes (PITCH=129 keeps phase-2 reads conflict-free;
                // float4 write would be 16B-misaligned for odd rows)
#pragma unroll
                for (int i = 0; i < 4; ++i)
                    s_sum[r * PITCH + f4 * 4 + i] = sums[i];
            }
        }
        __syncthreads();

        // ---------- phase 2: KAN contraction, lane = row, f wave-uniform ----------
        {
#pragma unroll 2
            for (int j = 0; j < FPW; ++j) {
                const int f = __builtin_amdgcn_readfirstlane(fbase + wave * FPW + j);
                const float sm = s_sum[lane * PITCH + (f - fbase)];

                const float s   = 0.99f * fast_tanh(sm);
                const float sil = sm * fast_sigmoid(sm);

                // phi = T_1..T_8 of s
                float phi[KB];
                float tkm1 = 1.0f, tk = s;
                const float s2 = 2.0f * s;
#pragma unroll
                for (int k = 0; k < KB; ++k) {
                    phi[k] = tk;
                    float tn = fmaf(s2, tk, -tkm1);
                    tkm1 = tk; tk = tn;
                }

                // weights are wave-uniform -> scalar loads, SGPR operands in FMA
#pragma unroll
                for (int c = 0; c < NC; ++c) {
                    const float* cf = coeff + (c * NF + f) * KB;
                    float a = acc[c];
#pragma unroll
                    for (int k = 0; k < KB; ++k)
                        a = fmaf(phi[k], cf[k], a);
                    acc[c] = fmaf(sil, base[c * NF + f], a);
                }
            }
        }
        __syncthreads();
    }

    // ---------- cross-wave reduction ----------
#pragma unroll
    for (int c = 0; c < NC; ++c)
        s_red[(wave * RB + lane) * NC + c] = acc[c];
    __syncthreads();

    for (int idx = t; idx < RB * NC; idx += NTHREADS) {
        const int r = idx / NC;
        const int c = idx - r * NC;
        float v = bias[c];
#pragma unroll
        for (int w = 0; w < NWAVES; ++w)
            v += s_red[(w * RB + r) * NC + c];
        out[(row0 + r) * NC + idx - r * NC] = v;
    }
}

extern "C" void kernel_launch(void* const* d_in, const int* in_sizes, int n_in,
                              void* d_out, int out_size, void* d_ws, size_t ws_size,
                              hipStream_t stream) {
    const float* X      = (const float*)d_in[0];
    const float* lcu_w  = (const float*)d_in[1];
    const float* alpha  = (const float*)d_in[2];
    const float* coeff  = (const float*)d_in[3];
    const float* base   = (const float*)d_in[4];
    const float* bias   = (const float*)d_in[5];
    float* out = (float*)d_out;

    qkan_kernel<<<BATCH / RB, NTHREADS, 0, stream>>>(X, lcu_w, alpha, coeff, base, bias, out);
}

// Round 2
// 118.885 us; speedup vs baseline: 2.2404x; 2.2404x over previous
//
#include <hip/hip_runtime.h>

#define BATCH 16384
#define NF    512
#define DEG   8
#define NC    10
#define KB    8

#define SPLITF 8
#define FC     (NF / SPLITF)     // 64 features per block
#define RB     64                // rows per block
#define PITCH  65                // 64+1: conflict-free phase-1 writes AND phase-2 reads
#define NT     256               // 4 waves
#define NWAVES 4
#define FPW    (FC / NWAVES)     // 16 features per wave in phase 2

__device__ __forceinline__ float fast_tanh(float x) {
    float e = __expf(2.0f * x);
    return 1.0f - 2.0f * __builtin_amdgcn_rcpf(e + 1.0f);
}
__device__ __forceinline__ float fast_sigmoid(float x) {
    return __builtin_amdgcn_rcpf(1.0f + __expf(-x));
}

// out[b][c] = bias[c]  (harness poisons d_out before every launch)
__global__ __launch_bounds__(256) void init_out(const float* __restrict__ bias,
                                                float* __restrict__ out) {
    int i = blockIdx.x * 256 + threadIdx.x;
    if (i < BATCH * NC) out[i] = bias[i % NC];
}

__global__ __launch_bounds__(NT) void qkan_kernel(
    const float* __restrict__ X,        // (B, F)
    const float* __restrict__ lcu_w,    // (F, DEG)
    const float* __restrict__ alpha,    // (F, DEG)
    const float* __restrict__ coeff,    // (C, F, KB)
    const float* __restrict__ base,     // (C, F)
    float* __restrict__ out)            // (B, C), pre-filled with bias
{
    // One buffer, reused: phase-1/2 summed tile (RB*PITCH = 4160 floats),
    // then cross-wave reduce scratch (NWAVES*RB*NC = 2560 floats).
    __shared__ float s_mem[RB * PITCH];   // 16.6 KB

    const int t      = threadIdx.x;
    const int rowblk = blockIdx.x >> 3;          // 0..255
    const int fsplit = blockIdx.x & (SPLITF - 1);
    const int row0   = rowblk * RB;
    const int fbase  = fsplit * FC;
    const int wave   = __builtin_amdgcn_readfirstlane(t >> 6);
    const int lane   = t & 63;

    // ---------------- phase 1: elementwise -> summed(b,f) into LDS ----------
    {
        const int f2   = t & 31;      // this thread's feature pair: fA, fA+1
        const int rsub = t >> 5;      // 0..7
        const int fA   = fbase + f2 * 2;

        // Row-invariant per-feature state: lcu weights, phases, 1/l1norm.
        float w[2][DEG], a[2][DEG], rden[2];
#pragma unroll
        for (int i = 0; i < 2; ++i) {
            const float4 w0 = *(const float4*)(lcu_w + (fA + i) * DEG);
            const float4 w1 = *(const float4*)(lcu_w + (fA + i) * DEG + 4);
            const float4 a0 = *(const float4*)(alpha + (fA + i) * DEG);
            const float4 a1 = *(const float4*)(alpha + (fA + i) * DEG + 4);
            w[i][0]=w0.x; w[i][1]=w0.y; w[i][2]=w0.z; w[i][3]=w0.w;
            w[i][4]=w1.x; w[i][5]=w1.y; w[i][6]=w1.z; w[i][7]=w1.w;
            a[i][0]=a0.x; a[i][1]=a0.y; a[i][2]=a0.z; a[i][3]=a0.w;
            a[i][4]=a1.x; a[i][5]=a1.y; a[i][6]=a1.z; a[i][7]=a1.w;
            float den = 1e-8f;
#pragma unroll
            for (int d = 0; d < DEG; ++d) den += fabsf(w[i][d]);
            rden[i] = __builtin_amdgcn_rcpf(den);
        }

#pragma unroll
        for (int it = 0; it < RB / 8; ++it) {
            const int r = rsub + it * 8;
            const float2 xv = *(const float2*)(X + (row0 + r) * NF + fA);
            float xs[2] = {xv.x, xv.y};
#pragma unroll
            for (int i = 0; i < 2; ++i) {
                const float x  = 0.99f * fast_tanh(xs[i]);
                const float x2 = 2.0f * x;
                float tkm1 = 1.0f, tk = x, num = 0.0f;
#pragma unroll
                for (int d = 0; d < DEG; ++d) {
                    num = fmaf(w[i][d], tk, num);
                    float tn = fmaf(x2, tk, -tkm1);
                    tkm1 = tk; tk = tn;
                }
                const float lcu = num * rden[i];
                float ss = 0.0f;
#pragma unroll
                for (int d = 0; d < DEG; ++d)
                    ss += __sinf(lcu * a[i][d]);
                s_mem[r * PITCH + f2 * 2 + i] = 0.125f * ss;
            }
        }
    }
    __syncthreads();

    // ------------- phase 2: KAN contraction, lane = row, f wave-uniform -----
    float acc[NC];
#pragma unroll
    for (int c = 0; c < NC; ++c) acc[c] = 0.0f;

#pragma unroll 2
    for (int j = 0; j < FPW; ++j) {
        const int foff = wave * FPW + j;                    // 0..63 in chunk
        const int f    = __builtin_amdgcn_readfirstlane(fbase + foff);
        const float sm = s_mem[lane * PITCH + foff];

        const float s   = 0.99f * fast_tanh(sm);
        const float sil = sm * fast_sigmoid(sm);

        float phi[KB];
        {
            float tkm1 = 1.0f, tk = s;
            const float s2 = 2.0f * s;
#pragma unroll
            for (int k = 0; k < KB; ++k) {
                phi[k] = tk;
                float tn = fmaf(s2, tk, -tkm1);
                tkm1 = tk; tk = tn;
            }
        }
        // f wave-uniform -> these are scalar (SGPR) loads; FMA uses SGPR src.
#pragma unroll
        for (int c = 0; c < NC; ++c) {
            const float* cf = coeff + (c * NF + f) * KB;
            float v = acc[c];
#pragma unroll
            for (int k = 0; k < KB; ++k)
                v = fmaf(phi[k], cf[k], v);
            acc[c] = fmaf(sil, base[c * NF + f], v);
        }
    }
    __syncthreads();   // before reusing s_mem as reduce scratch

    // ------------- cross-wave reduce (4 partial sums per row,c) -------------
#pragma unroll
    for (int c = 0; c < NC; ++c)
        s_mem[(wave * RB + lane) * NC + c] = acc[c];
    __syncthreads();

    for (int idx = t; idx < RB * NC; idx += NT) {
        const int r = idx / NC;
        const int c = idx - r * NC;
        float v = s_mem[idx];                       // wave 0 partial
#pragma unroll
        for (int w = 1; w < NWAVES; ++w)
            v += s_mem[(w * RB + r) * NC + c];
        unsafeAtomicAdd(out + (row0 + r) * NC + c, v);
    }
}

extern "C" void kernel_launch(void* const* d_in, const int* in_sizes, int n_in,
                              void* d_out, int out_size, void* d_ws, size_t ws_size,
                              hipStream_t stream) {
    const float* X      = (const float*)d_in[0];
    const float* lcu_w  = (const float*)d_in[1];
    const float* alpha  = (const float*)d_in[2];
    const float* coeff  = (const float*)d_in[3];
    const float* base   = (const float*)d_in[4];
    const float* bias   = (const float*)d_in[5];
    float* out = (float*)d_out;

    init_out<<<(BATCH * NC + 255) / 256, 256, 0, stream>>>(bias, out);
    qkan_kernel<<<(BATCH / RB) * SPLITF, NT, 0, stream>>>(X, lcu_w, alpha, coeff, base, out);
}